// Round 7
// baseline (298.091 us; speedup 1.0000x reference)
//
#include <hip/hip_runtime.h>

// ---------------------------------------------------------------------------
// CausalSelfAttention: y = proj(attn(qkv(x)))  B=4 T=2048 E=1024 H=16 D=64
// Mask: rows<512 attend cols<512 (full); rows>=512 causal.
// R7: (a) attn grid transposed to (bh, slot): linear id % 8 = bh % 8 ->
//     all chunks of one bh share an XCD -> K/V re-reads hit L2, split-K
//     atomics coalesce in one L2 (R6: FETCH 2.2x unique, WRITE ~= all
//     atomics spilled to HBM). (b) combine kernel deleted: gemm_proj
//     normalizes Oacc f32 by Rsum during A-staging (ds_write path).
// ---------------------------------------------------------------------------

typedef _Float16 f16;
typedef _Float16 f16x4 __attribute__((ext_vector_type(4)));
typedef _Float16 f16x8 __attribute__((ext_vector_type(8)));
typedef float f32x4 __attribute__((ext_vector_type(4)));

#define MFMA16x32(a, b, c) __builtin_amdgcn_mfma_f32_16x16x32_f16(a, b, c, 0, 0, 0)
#define MFMA16x16(a, b, c) __builtin_amdgcn_mfma_f32_16x16x16f16(a, b, c, 0, 0, 0)

__device__ __forceinline__ void gload_lds16(const void* g, void* l) {
  __builtin_amdgcn_global_load_lds(
      (__attribute__((address_space(1))) void*)g,
      (__attribute__((address_space(3))) void*)l, 16, 0, 0);
}

// --------------------------- prep kernels ----------------------------------

__global__ void k_cast_f16(const float* __restrict__ x, f16* __restrict__ xh) {
  int i = blockIdx.x * 256 + threadIdx.x;
  float4 v = ((const float4*)x)[i];
  f16x4 o = {(f16)v.x, (f16)v.y, (f16)v.z, (f16)v.w};
  ((f16x4*)xh)[i] = o;
}

// W [Kdim][Ndim] f32  ->  Wt [Ndim][Kdim] f16
__global__ void k_transpose(const float* __restrict__ W, f16* __restrict__ Wt,
                            int Kdim, int Ndim) {
  __shared__ float tile[32][33];
  int n = blockIdx.x * 32 + threadIdx.x;
  int k0 = blockIdx.y * 32;
  for (int j = threadIdx.y; j < 32; j += 8)
    tile[j][threadIdx.x] = W[(size_t)(k0 + j) * Ndim + n];
  __syncthreads();
  int k = k0 + threadIdx.x;
  for (int j = threadIdx.y; j < 32; j += 8)
    Wt[(size_t)(blockIdx.x * 32 + j) * Kdim + k] = (f16)tile[threadIdx.x][j];
}

// --------------------------- GEMM1: x @ W_qkv -------------------------------
// A [8192][1024] f16, Bt [3072][1024] f16 (W^T). LDS-staged epilogue emits
// b128 coalesced stores to Q[bh][t][d], K[bh][t][d], Vt[bh][d][t].

__global__ __launch_bounds__(256) void k_gemm_qkv(
    const f16* __restrict__ A, const f16* __restrict__ Bt,
    const float* __restrict__ bias,
    f16* __restrict__ Qo, f16* __restrict__ Ko, f16* __restrict__ Vo) {
  constexpr int KD = 1024;
  __shared__ __align__(16) f16 As[128 * 32];
  __shared__ __align__(16) f16 Bs[128 * 32];
  __shared__ __align__(16) f16 Esh[4 * 64 * 72];  // per-wave epilogue stage
  const int tid = threadIdx.x;
  const int wave = tid >> 6, lane = tid & 63;
  const int g = lane >> 4, l16 = lane & 15;
  const int m0 = blockIdx.y * 128, n0 = blockIdx.x * 128;
  const int wm = (wave >> 1) * 64, wn = (wave & 1) * 64;
  const int srow = wave * 16 + (lane >> 2);
  const int skc = (lane & 3) * 8;

  f32x4 acc[4][4] = {};

  for (int k0 = 0; k0 < KD; k0 += 32) {
    __syncthreads();
    for (int it = 0; it < 2; ++it) {
      gload_lds16(A + (size_t)(m0 + it * 64 + srow) * KD + k0 + skc,
                  As + (it * 64 + wave * 16) * 32);
      gload_lds16(Bt + (size_t)(n0 + it * 64 + srow) * KD + k0 + skc,
                  Bs + (it * 64 + wave * 16) * 32);
    }
    __syncthreads();
    f16x8 af[4], bf[4];
    for (int mi = 0; mi < 4; ++mi)
      af[mi] = *(const f16x8*)(As + (wm + mi * 16 + l16) * 32 + g * 8);
    for (int ni = 0; ni < 4; ++ni)
      bf[ni] = *(const f16x8*)(Bs + (wn + ni * 16 + l16) * 32 + g * 8);
    for (int mi = 0; mi < 4; ++mi)
      for (int ni = 0; ni < 4; ++ni)
        acc[mi][ni] = MFMA16x32(af[mi], bf[ni], acc[mi][ni]);
  }

  // ---- epilogue: per-wave LDS stage -> b128 coalesced stores ----
  const int nsub = n0 + wn;            // multiple of 64 -> one (part, head)
  const int part = nsub >> 10;         // 0=Q 1=K 2=V
  const int h    = (nsub >> 6) & 15;
  const int mg   = m0 + wm;
  const int b    = mg >> 11;
  const int tb   = mg & 2047;
  const size_t bh = (size_t)(b * 16 + h);
  f16* Es = Esh + wave * (64 * 72);

  float bv[4];
  for (int ni = 0; ni < 4; ++ni) bv[ni] = bias[nsub + ni * 16 + l16];

  for (int mi = 0; mi < 4; ++mi)
    for (int ni = 0; ni < 4; ++ni)
      for (int r = 0; r < 4; ++r) {
        f16 hv = (f16)(acc[mi][ni][r] + bv[ni]);
        int mrow = mi * 16 + g * 4 + r, ncol = ni * 16 + l16;
        if (part == 2) Es[ncol * 72 + mrow] = hv;   // store transposed: [d][t]
        else           Es[mrow * 72 + ncol] = hv;   // [t][d]
      }
  // same-wave DS write->read: LDS pipe in-order, no barrier needed

  const int rrow = lane >> 3, rcol = (lane & 7) * 8;
  for (int p = 0; p < 8; ++p) {
    int row = p * 8 + rrow;
    f16x8 vv = *(const f16x8*)(Es + row * 72 + rcol);
    if (part == 0)
      *(f16x8*)(Qo + (bh * 2048 + tb + row) * 64 + rcol) = vv;
    else if (part == 1)
      *(f16x8*)(Ko + (bh * 2048 + tb + row) * 64 + rcol) = vv;
    else  // row is d, rcol is t-offset
      *(f16x8*)(Vo + (bh * 64 + row) * 2048 + tb + rcol) = vv;
  }
}

// --------------------------- flash attention (split-K) ----------------------
// grid (64 bh, 40 chunk-slots): linear id = bh + 64*slot -> id%8 = bh%8 ->
// all chunks of a bh share one XCD (L2 locality for K/V + atomic coalescing).
// Chunk table maps slot -> (q-tile, first k-tile); <=8 k-tiles per chunk.
// Partial O (unnormalized, f32) and rsum accumulate via device atomicAdd.

__constant__ unsigned char cQT[40] = {0, 1, 2,  3,  4,  4,  5,  5,  6,  6,
                                      7, 7, 8,  8,  8,  9,  9,  9,  10, 10,
                                      10, 11, 11, 11, 12, 12, 12, 12, 13, 13,
                                      13, 13, 14, 14, 14, 14, 15, 15, 15, 15};
__constant__ unsigned char cC0[40] = {0, 0, 0, 0,  0, 8, 0, 8, 0, 8,
                                      0, 8, 0, 8,  16, 0, 8, 16, 0, 8,
                                      16, 0, 8, 16, 0, 8, 16, 24, 0, 8,
                                      16, 24, 0, 8, 16, 24, 0, 8, 16, 24};

__global__ __launch_bounds__(256, 4) void k_attn(
    const f16* __restrict__ Q, const f16* __restrict__ Kb,
    const f16* __restrict__ Vt, float* __restrict__ Oacc,
    float* __restrict__ Rsum) {
  __shared__ __align__(16) f16 Ks[64 * 64];
  __shared__ __align__(16) f16 Vs[64 * 64];

  const int tid = threadIdx.x;
  const int wave = tid >> 6, lane = tid & 63;
  const int g = lane >> 4, l16 = lane & 15;
  const int bh = blockIdx.x;
  const int qt = cQT[blockIdx.y];
  const int c0 = cC0[blockIdx.y];
  const int q0 = qt * 128;
  const int nt = (qt < 4) ? 8 : (qt + 1) * 2;   // total k-tiles for this qt
  const int it_n = min(8, nt - c0);             // this chunk's tile count

  // Q B-fragments (operand-swapped QK), pre-scaled by log2(e)/8
  f16x8 aq[2][2];
  for (int mi = 0; mi < 2; ++mi) {
    const f16* qrow =
        Q + ((size_t)bh * 2048 + q0 + wave * 32 + mi * 16 + l16) * 64 + g * 8;
    aq[mi][0] = *(const f16x8*)(qrow);
    aq[mi][1] = *(const f16x8*)(qrow + 32);
    for (int kb = 0; kb < 2; ++kb)
      aq[mi][kb] = aq[mi][kb] * (f16)0.18033688f;
  }

  f32x4 o[2][4] = {};       // o[mi][db]: O[m=g*4+r][d=db*16+l16]
  float rsum[2] = {};       // per-lane partial for row m=l16 (quad's k share)
  const int srowrel = lane >> 3;
  const int sc = (lane & 7) ^ srowrel;  // XOR-swizzled staging chunk

  const f32x4 sinit = {-8.65617025f, -8.65617025f, -8.65617025f, -8.65617025f};

  for (int i = 0; i < it_n; ++i) {
    const int kt0 = (c0 + i) << 6;
    __syncthreads();
    for (int it = 0; it < 2; ++it) {
      int row = it * 32 + wave * 8 + srowrel;
      gload_lds16(Kb + ((size_t)bh * 2048 + kt0 + row) * 64 + sc * 8,
                  Ks + (it * 32 + wave * 8) * 64);
      gload_lds16(Vt + ((size_t)bh * 64 + row) * 2048 + kt0 + sc * 8,
                  Vs + (it * 32 + wave * 8) * 64);
    }
    __syncthreads();

    // T = K Q^T : T[k=g*4+r][m=l16] per nb (k-block), mi (q-block)
    f32x4 t[2][4];
    for (int nb = 0; nb < 4; ++nb) {
      int R = nb * 16 + l16, sw = R & 7;
      f16x8 bk0 = *(const f16x8*)(Ks + R * 64 + ((0 + g) ^ sw) * 8);
      f16x8 bk1 = *(const f16x8*)(Ks + R * 64 + ((4 + g) ^ sw) * 8);
      for (int mi = 0; mi < 2; ++mi) {
        f32x4 acc = MFMA16x32(bk0, aq[mi][0], sinit);
        t[mi][nb] = MFMA16x32(bk1, aq[mi][1], acc);
      }
    }

    // exp -> P stays in registers as 16x16x16 A-frags ap[nb][mi]
    const bool masked = (q0 >= 512) && (kt0 >= q0);
    f16x4 ap[4][2];
    for (int mi = 0; mi < 2; ++mi) {
      const int mrow = q0 + wave * 32 + mi * 16 + l16;
      for (int nb = 0; nb < 4; ++nb)
        for (int r = 0; r < 4; ++r) {
          float p = __builtin_amdgcn_exp2f(t[mi][nb][r]);
          if (masked && (kt0 + nb * 16 + g * 4 + r > mrow)) p = 0.f;
          rsum[mi] += p;
          ap[nb][mi][r] = (f16)p;
        }
    }

    // O += P V : A = ap (in-register), B = V^T b64 frags from LDS
    for (int db = 0; db < 4; ++db)
      for (int nb = 0; nb < 4; ++nb) {
        int R = db * 16 + l16, sw = R & 7;
        int c = nb * 2 + (g >> 1);
        f16x4 bv = *(const f16x4*)(Vs + R * 64 + (c ^ sw) * 8 + (g & 1) * 4);
        for (int mi = 0; mi < 2; ++mi)
          o[mi][db] = MFMA16x16(ap[nb][mi], bv, o[mi][db]);
      }
  }

  // reduce rsum across quads: all lanes with same l16 get the row total
  for (int mi = 0; mi < 2; ++mi) {
    rsum[mi] += __shfl_xor(rsum[mi], 16, 64);
    rsum[mi] += __shfl_xor(rsum[mi], 32, 64);
  }

  const size_t rowbase = (size_t)bh * 2048 + q0 + wave * 32;
  if (lane < 16)
    for (int mi = 0; mi < 2; ++mi)
      atomicAdd(&Rsum[rowbase + mi * 16 + l16], rsum[mi]);
  for (int mi = 0; mi < 2; ++mi)
    for (int db = 0; db < 4; ++db)
      for (int r = 0; r < 4; ++r)
        atomicAdd(&Oacc[(rowbase + mi * 16 + g * 4 + r) * 64 + db * 16 + l16],
                  o[mi][db][r]);
}

// --------------------------- GEMM2: (Oacc/Rsum) @ W_proj --------------------
// A logical [8192][1024] f16 where A[b*2048+t][h*64+d] = Oacc[b*16+h][t][d]
// / Rsum[b*16+h][t], normalized+cvt during LDS staging (combine kernel fused).

__global__ __launch_bounds__(256) void k_gemm_proj(
    const float* __restrict__ Oacc, const float* __restrict__ Rsum,
    const f16* __restrict__ Bt, const float* __restrict__ bias,
    float* __restrict__ out) {
  constexpr int KD = 1024;
  __shared__ __align__(16) f16 As[128 * 32];
  __shared__ __align__(16) f16 Bs[128 * 32];
  const int tid = threadIdx.x;
  const int wave = tid >> 6, lane = tid & 63;
  const int g = lane >> 4, l16 = lane & 15;
  const int m0 = blockIdx.y * 128, n0 = blockIdx.x * 128;
  const int wm = (wave >> 1) * 64, wn = (wave & 1) * 64;
  const int srow = wave * 16 + (lane >> 2);  // staging row 0..63 within half
  const int skc = (lane & 3) * 8;            // staging col chunk (8 elems)
  const int b = m0 >> 11;                    // block spans one batch

  f32x4 acc[4][4] = {};

  for (int k0 = 0; k0 < KD; k0 += 32) {
    const int h = k0 >> 6;                   // head for this k-block
    const int d0 = (k0 & 63) + skc;          // d-offset within head
    __syncthreads();
    for (int it = 0; it < 2; ++it) {
      // A: load 8 f32 from Oacc, normalize, cvt, ds_write b128
      int t = (m0 & 2047) + it * 64 + srow;
      const float* op =
          Oacc + ((size_t)(b * 16 + h) * 2048 + t) * 64 + d0;
      float4 v0 = *(const float4*)(op);
      float4 v1 = *(const float4*)(op + 4);
      float rinv = 1.0f / Rsum[(size_t)(b * 16 + h) * 2048 + t];
      f16x8 w = {(f16)(v0.x * rinv), (f16)(v0.y * rinv), (f16)(v0.z * rinv),
                 (f16)(v0.w * rinv), (f16)(v1.x * rinv), (f16)(v1.y * rinv),
                 (f16)(v1.z * rinv), (f16)(v1.w * rinv)};
      *(f16x8*)(As + (it * 64 + srow) * 32 + skc) = w;
      // B: async staged as before
      gload_lds16(Bt + (size_t)(n0 + it * 64 + srow) * KD + k0 + skc,
                  Bs + (it * 64 + wave * 16) * 32);
    }
    __syncthreads();
    f16x8 af[4], bf[4];
    for (int mi = 0; mi < 4; ++mi)
      af[mi] = *(const f16x8*)(As + (wm + mi * 16 + l16) * 32 + g * 8);
    for (int ni = 0; ni < 4; ++ni)
      bf[ni] = *(const f16x8*)(Bs + (wn + ni * 16 + l16) * 32 + g * 8);
    for (int mi = 0; mi < 4; ++mi)
      for (int ni = 0; ni < 4; ++ni)
        acc[mi][ni] = MFMA16x32(af[mi], bf[ni], acc[mi][ni]);
  }

  float bv[4];
  for (int ni = 0; ni < 4; ++ni) bv[ni] = bias[n0 + wn + ni * 16 + l16];

  for (int mi = 0; mi < 4; ++mi)
    for (int ni = 0; ni < 4; ++ni)
      for (int r = 0; r < 4; ++r) {
        int m = m0 + wm + mi * 16 + g * 4 + r;
        int n = n0 + wn + ni * 16 + l16;
        out[(size_t)m * 1024 + n] = acc[mi][ni][r] + bv[ni];
      }
}

// --------------------------- launch ----------------------------------------

extern "C" void kernel_launch(void* const* d_in, const int* in_sizes, int n_in,
                              void* d_out, int out_size, void* d_ws,
                              size_t ws_size, hipStream_t stream) {
  const float* x      = (const float*)d_in[0];
  const float* W_qkv  = (const float*)d_in[1];
  const float* b_qkv  = (const float*)d_in[2];
  const float* W_proj = (const float*)d_in[3];
  const float* b_proj = (const float*)d_in[4];
  float* out = (float*)d_out;

  char* ws = (char*)d_ws;
  f16* xh    = (f16*)ws;   ws += (size_t)8192 * 1024 * 2;
  f16* Wqt   = (f16*)ws;   ws += (size_t)3072 * 1024 * 2;
  f16* Wpt   = (f16*)ws;   ws += (size_t)1024 * 1024 * 2;
  f16* Qb    = (f16*)ws;   ws += (size_t)64 * 2048 * 64 * 2;
  f16* Kb    = (f16*)ws;   ws += (size_t)64 * 2048 * 64 * 2;
  f16* Vt    = (f16*)ws;   ws += (size_t)64 * 64 * 2048 * 2;
  float* Oacc = (float*)ws; ws += (size_t)64 * 2048 * 64 * 4;
  float* Rsum = (float*)ws; ws += (size_t)64 * 2048 * 4;

  // zero the split-K accumulators (Oacc + Rsum contiguous)
  hipMemsetAsync(Oacc, 0, (size_t)64 * 2048 * 64 * 4 + (size_t)64 * 2048 * 4,
                 stream);

  k_cast_f16<<<8192, 256, 0, stream>>>(x, xh);
  k_transpose<<<dim3(96, 32), dim3(32, 8), 0, stream>>>(W_qkv, Wqt, 1024, 3072);
  k_transpose<<<dim3(32, 32), dim3(32, 8), 0, stream>>>(W_proj, Wpt, 1024, 1024);
  k_gemm_qkv<<<dim3(24, 64), 256, 0, stream>>>(xh, Wqt, b_qkv, Qb, Kb, Vt);
  k_attn<<<dim3(64, 40), 256, 0, stream>>>(Qb, Kb, Vt, Oacc, Rsum);
  k_gemm_proj<<<dim3(8, 64), 256, 0, stream>>>(Oacc, Rsum, Wpt, b_proj, out);
}